// Round 12
// baseline (107.813 us; speedup 1.0000x reference)
//
#include <hip/hip_runtime.h>

// Problem constants (from reference)
#define B 1024
#define R 256
#define D 512
#define G 4

#define LOG2E 1.44269504088896340736f

// Workspace layout (float offsets). Total = 2,894,848 floats = 11.58 MB.
// PB: per (r, chunk-of-2-d): [fb(2) | fa(2) | q0(2) | q1(2) | q2(2) | q3(2)] = 12 floats (48 B)
//   t = fa*x + fb ; exp2(t) = exp(-kappa*ineq*(x-th)) ; sigmoid = 1/(1+exp2(t))
//   qg = sigmoid(ml)*tanh(esp)*softmax(A)_g
#define OFF_PB   0                         // [R][256][12]
#define OFF_EPI  (R*256*12)                // [R][12]  {offe0..3, gm0..3, k8e, hw, pad, pad}
#define OFF_PART (OFF_EPI + R*12)          // [R][2 dh][B][4 g] raw acc partials
#define OFF_ZP   (OFF_PART + R*2*B*4)      // [8][B]   per-r-slice partial of y
#define NBT 16                             // b-tiles (64 b per block)

typedef float f2 __attribute__((ext_vector_type(2)));
static __device__ __forceinline__ f2 mk2(float a, float b) { f2 v; v.x = a; v.y = b; return v; }

__device__ __forceinline__ float rcp_f(float v)  { return __builtin_amdgcn_rcpf(v); }
__device__ __forceinline__ float exp2_f(float v) { return __builtin_amdgcn_exp2f(v); }
__device__ __forceinline__ float sig_f(float v)  { return rcp_f(1.0f + exp2_f(-v * LOG2E)); }
__device__ __forceinline__ float tanh_f(float v) {
    const float q2 = exp2_f(v * (2.0f * LOG2E));
    return (q2 - 1.0f) * rcp_f(q2 + 1.0f);
}

// ---------------- Kernel 1: fold all b-independent math (proven, R7-R11) ----------------
__global__ __launch_bounds__(256)
void sge_precompute(const float* __restrict__ th,  const float* __restrict__ isp,
                    const float* __restrict__ esp, const float* __restrict__ ml,
                    const float* __restrict__ lk,  const float* __restrict__ gl,
                    const float* __restrict__ tg,  const float* __restrict__ gml,
                    const float* __restrict__ kf,  const float* __restrict__ hw,
                    float* __restrict__ ws)
{
    const int r   = blockIdx.x;
    const int tid = threadIdx.x;
    __shared__ float4 red[256];

    float kappa = exp2_f(lk[0] * LOG2E);
    kappa = fminf(fmaxf(kappa, 0.5f), 50.0f);

    float4 psum = make_float4(0.f, 0.f, 0.f, 0.f);
    for (int d = tid; d < D; d += 256) {
        const int idx = r * D + d;
        const float thv  = th[idx];
        const float ineq = tanh_f(isp[idx]);
        const float es   = tanh_f(esp[idx]);
        const float mm   = sig_f(ml[idx]);
        const float g0 = gl[0*D + d], g1 = gl[1*D + d], g2 = gl[2*D + d], g3 = gl[3*D + d];
        const float mx = fmaxf(fmaxf(g0, g1), fmaxf(g2, g3));
        const float e0 = exp2_f((g0 - mx) * LOG2E), e1 = exp2_f((g1 - mx) * LOG2E);
        const float e2 = exp2_f((g2 - mx) * LOG2E), e3 = exp2_f((g3 - mx) * LOG2E);
        const float inv = 1.0f / (e0 + e1 + e2 + e3);
        const float a0 = e0 * inv, a1 = e1 * inv, a2 = e2 * inv, a3 = e3 * inv;

        const float fa = -kappa * ineq * LOG2E;   // exp2(fa*x+fb) == exp(-kappa*ineq*(x-th))
        const float fb = -fa * thv;
        const float s  = mm * es;
        const float s0 = s * a0, s1 = s * a1, s2 = s * a2, s3 = s * a3;

        const int chunk = d >> 1, j = d & 1;
        float* pc = ws + OFF_PB + ((size_t)r * 256 + chunk) * 12;
        pc[j]      = fb;
        pc[2 + j]  = fa;
        pc[4 + j]  = s0;
        pc[6 + j]  = s1;
        pc[8 + j]  = s2;
        pc[10 + j] = s3;
        psum.x += s0; psum.y += s1; psum.z += s2; psum.w += s3;
    }
    red[tid] = psum;
    __syncthreads();
    for (int s = 128; s > 0; s >>= 1) {
        if (tid < s) {
            red[tid].x += red[tid + s].x;
            red[tid].y += red[tid + s].y;
            red[tid].z += red[tid + s].z;
            red[tid].w += red[tid + s].w;
        }
        __syncthreads();
    }
    if (tid == 0) {
        const float4 base = red[0];
        const float gm0 = sig_f(gml[r * G + 0]);
        const float gm1 = sig_f(gml[r * G + 1]);
        const float gm2 = sig_f(gml[r * G + 2]);
        const float gm3 = sig_f(gml[r * G + 3]);
        const float en  = gm0 + gm1 + gm2 + gm3 + 1e-6f;
        const float k   = sig_f(kf[r]) * en;
        float* epi = ws + OFF_EPI + r * 12;
        epi[0] = 6.0f * (base.x + tg[r * G + 0]) * LOG2E;
        epi[1] = 6.0f * (base.y + tg[r * G + 1]) * LOG2E;
        epi[2] = 6.0f * (base.z + tg[r * G + 2]) * LOG2E;
        epi[3] = 6.0f * (base.w + tg[r * G + 3]) * LOG2E;
        epi[4] = gm0; epi[5] = gm1; epi[6] = gm2; epi[7] = gm3;
        epi[8] = 8.0f * k * LOG2E;
        epi[9] = hw[r];
        epi[10] = 0.f; epi[11] = 0.f;
    }
}

// ---------------- Kernel 2: the 134M-element hot loop ----------------
// Grid: 16 b-tiles x (32 r-blocks x 2 d-halves) = 1024 blocks, 66 KB LDS -> 2
// blocks/CU = 16 waves/CU (4/SIMD). Block: 512 thr = 8 waves; wave w owns ONE r
// (rblk*8+w) over 64 b (lane = b) x 256 d in 128 2-d chunks.
//   x: staged ONCE in LDS, 1 ds_read_b64/chunk (in-order lgkm, ~70cy, dist-1 A/B).
//   params: VMEM BROADCAST float4 x3/chunk (vz trick keeps them vector -> in-order
//     vmcnt, precise vmcnt(6) waits), 3-slot rotation at distance 2 phases
//     (~84cy x 4 waves/SIMD = 336cy cover > L2 latency). NOT s_load: SMEM
//     completes out-of-order -> any consumption forces lgkmcnt(0) full drain
//     including the just-issued prefetch (the ~55% VALUBusy cap of R3/R6/R7).
//   live set ~56 VGPR: fits the allocator's hard 64-VGPR target (R9/R10's ~110
//     spilled; R11's sank). sched_barrier(0) per phase forbids re-sinking.
struct PB4 { float4 a, b, c; };   // one chunk's params: {fb2|fa2},{q0|q1},{q2|q3}

__global__ __launch_bounds__(512)
void sge_main(const float* __restrict__ x, const float* __restrict__ ws,
              float* __restrict__ part)
{
    __shared__ float xl[64 * 258];   // 66 KB: 64 b rows x 256 d, pitch 258 (2-way=free)

    const int tid  = threadIdx.x;
    const int lane = tid & 63;
    const int w    = __builtin_amdgcn_readfirstlane(tid >> 6);
    const int bt   = blockIdx.x;          // 0..15
    const int rbdh = blockIdx.y;          // 0..63
    const int rblk = rbdh >> 1;           // 0..31
    const int dh   = rbdh & 1;            // d-half 0..1
    const int r    = rblk * 8 + w;

    // ---- stage x: 64 b x 256 d (this d-half) = 4096 float4, 8 iters of 512 thr ----
    #pragma unroll
    for (int k = 0; k < 8; ++k) {
        const int i   = tid + k * 512;
        const int row = i >> 6, c4 = i & 63;
        const float4 v = reinterpret_cast<const float4*>(x)[(size_t)(bt * 64 + row) * 128 + dh * 64 + c4];
        f2* dst = reinterpret_cast<f2*>(&xl[row * 258 + c4 * 4]);
        dst[0] = mk2(v.x, v.y);
        dst[1] = mk2(v.z, v.w);
    }
    __syncthreads();

    // opaque zero in a VGPR keeps param loads on the vector (vmcnt) path, not s_load
    int vz; asm volatile("v_mov_b32 %0, 0" : "=v"(vz));
    const float* pp = ws + OFF_PB + ((size_t)r * 256 + (size_t)dh * 128) * 12 + vz;

    f2 acc0 = mk2(0.f,0.f), acc1 = mk2(0.f,0.f), acc2 = mk2(0.f,0.f), acc3 = mk2(0.f,0.f);

    auto ldP = [&](PB4& P, int ch) {
        ch = (ch < 127) ? ch : 127;       // tail prefetch clamp (dup, harmless)
        const float4* q = reinterpret_cast<const float4*>(pp + (size_t)ch * 12);
        P.a = q[0]; P.b = q[1]; P.c = q[2];
    };
    auto ldX = [&](f2& xv, int ch) {
        xv = *reinterpret_cast<const f2*>(&xl[lane * 258 + ch * 2]);
    };
    auto compute = [&](const PB4& P, f2 xv) {
        const f2 t = __builtin_elementwise_fma(xv, mk2(P.a.z, P.a.w), mk2(P.a.x, P.a.y));
        f2 e;
        e.x = exp2_f(t.x); e.y = exp2_f(t.y);
        const f2 u = e + 1.0f;
        const float rp = rcp_f(u.x * u.y);        // one rcp per d-pair
        const f2 c = mk2(u.y, u.x) * mk2(rp, rp); // sigmoid pair {d0,d1}
        acc0 = __builtin_elementwise_fma(mk2(P.b.x, P.b.y), c, acc0);
        acc1 = __builtin_elementwise_fma(mk2(P.b.z, P.b.w), c, acc1);
        acc2 = __builtin_elementwise_fma(mk2(P.c.x, P.c.y), c, acc2);
        acc3 = __builtin_elementwise_fma(mk2(P.c.z, P.c.w), c, acc3);
    };

    PB4 A, Bs, C;
    f2 xa, xb;
    ldP(A, 0); ldP(Bs, 1); ldP(C, 2); ldX(xa, 0);

    // 6-phase body: slots rotate A,B,C (reload distance 2 phases on the in-order
    // vmcnt stream); x alternates xa/xb at distance 1 on lgkm. sched_barrier(0)
    // after each phase pins the software pipeline (R11: scheduler sank the
    // prefetches into uses, VGPR=32, serialized on L2 latency).
    #pragma unroll 1
    for (int c = 0; c < 126; c += 6) {
        ldX(xb, c + 1); compute(A,  xa); ldP(A,  c + 3);
        __builtin_amdgcn_sched_barrier(0);
        ldX(xa, c + 2); compute(Bs, xb); ldP(Bs, c + 4);
        __builtin_amdgcn_sched_barrier(0);
        ldX(xb, c + 3); compute(C,  xa); ldP(C,  c + 5);
        __builtin_amdgcn_sched_barrier(0);
        ldX(xa, c + 4); compute(A,  xb); ldP(A,  c + 6);
        __builtin_amdgcn_sched_barrier(0);
        ldX(xb, c + 5); compute(Bs, xa); ldP(Bs, c + 7);
        __builtin_amdgcn_sched_barrier(0);
        ldX(xa, c + 6); compute(C,  xb); ldP(C,  c + 8);
        __builtin_amdgcn_sched_barrier(0);
    }
    // tail: chunk 126 (slot A, xa), chunk 127 (slot B, xb)
    ldX(xb, 127);
    compute(A,  xa);
    compute(Bs, xb);

    // ---- write raw acc partials; finalize merges d-halves + nonlinear chain ----
    const float4 v0 = make_float4(acc0.x + acc0.y, acc1.x + acc1.y,
                                  acc2.x + acc2.y, acc3.x + acc3.y);
    reinterpret_cast<float4*>(part)[(size_t)(r * 2 + dh) * B + bt * 64 + lane] = v0;
}

// ---------------- Kernel 3a: nonlinear chain per (b,r), partial reduce over r ----------------
// Grid: 16 b-groups x 8 r-slices = 128 blocks x 256 thr (64 lanes=b, 4 subs x 8 r).
__global__ __launch_bounds__(256)
void sge_fin1(const float* __restrict__ part, const float* __restrict__ ws,
              float* __restrict__ zp)
{
    __shared__ float red[256];
    const int tid  = threadIdx.x;
    const int lane = tid & 63;
    const int sub  = tid >> 6;        // 0..3
    const int bg   = blockIdx.x;      // 0..15
    const int rs   = blockIdx.y;      // 0..7
    const int b    = bg * 64 + lane;
    const float C12 = -12.0f * LOG2E;
    const float C8  = -8.0f  * LOG2E;

    float s = 0.f;
    #pragma unroll 1
    for (int rr = 0; rr < 8; ++rr) {
        const int r = rs * 32 + sub * 8 + rr;
        const float4 v0 = reinterpret_cast<const float4*>(part)[(size_t)(r * 2 + 0) * B + b];
        const float4 v1 = reinterpret_cast<const float4*>(part)[(size_t)(r * 2 + 1) * B + b];
        const float a0 = v0.x + v1.x;
        const float a1 = v0.y + v1.y;
        const float a2 = v0.z + v1.z;
        const float a3 = v0.w + v1.w;
        const float* epi = ws + OFF_EPI + r * 12;
        const float pg0 = rcp_f(1.0f + exp2_f(fmaf(C12, a0, epi[0])));
        const float pg1 = rcp_f(1.0f + exp2_f(fmaf(C12, a1, epi[1])));
        const float pg2 = rcp_f(1.0f + exp2_f(fmaf(C12, a2, epi[2])));
        const float pg3 = rcp_f(1.0f + exp2_f(fmaf(C12, a3, epi[3])));
        float score = pg0 * epi[4];
        score = fmaf(pg1, epi[5], score);
        score = fmaf(pg2, epi[6], score);
        score = fmaf(pg3, epi[7], score);
        const float z = rcp_f(1.0f + exp2_f(fmaf(C8, score, epi[8])));
        s = fmaf(epi[9], z, s);
    }
    red[tid] = s;
    __syncthreads();
    if (sub == 0)
        zp[(size_t)rs * B + b] = red[lane] + red[64 + lane] + red[128 + lane] + red[192 + lane];
}

// ---------------- Kernel 3b: final deterministic sum over r-slices ----------------
__global__ __launch_bounds__(256)
void sge_fin2(const float* __restrict__ zp, const float* __restrict__ hb,
              float* __restrict__ y)
{
    const int b = blockIdx.x * 256 + threadIdx.x;
    float s = hb[0];
    #pragma unroll
    for (int k = 0; k < 8; ++k) s += zp[(size_t)k * B + b];
    y[b] = s;
}

extern "C" void kernel_launch(void* const* d_in, const int* in_sizes, int n_in,
                              void* d_out, int out_size, void* d_ws, size_t ws_size,
                              hipStream_t stream)
{
    const float* x   = (const float*)d_in[0];
    const float* th  = (const float*)d_in[1];
    const float* isp = (const float*)d_in[2];
    const float* esp = (const float*)d_in[3];
    const float* ml  = (const float*)d_in[4];
    const float* lk  = (const float*)d_in[5];
    const float* gl  = (const float*)d_in[6];
    const float* tg  = (const float*)d_in[7];
    const float* gml = (const float*)d_in[8];
    const float* kf  = (const float*)d_in[9];
    const float* hw  = (const float*)d_in[10];
    const float* hb  = (const float*)d_in[11];
    float* ws = (float*)d_ws;
    float* y  = (float*)d_out;

    sge_precompute<<<R, 256, 0, stream>>>(th, isp, esp, ml, lk, gl, tg, gml, kf, hw, ws);
    sge_main<<<dim3(NBT, 64), 512, 0, stream>>>(x, ws, ws + OFF_PART);
    sge_fin1<<<dim3(16, 8), 256, 0, stream>>>(ws + OFF_PART, ws, ws + OFF_ZP);
    sge_fin2<<<B / 256, 256, 0, stream>>>(ws + OFF_ZP, hb, y);
}